// Round 2
// baseline (8238.947 us; speedup 1.0000x reference)
//
#include <hip/hip_runtime.h>
#include <math.h>

// Problem constants (match reference)
#define NATOM_FEAT 24   // IPSIN * NWAVE = 3*8
#define PORI 13
#define NW 8
#define HID 128

// -------- edge scatter: compute radial[13][8] per edge, atomic-add into orbital[center] --------
template<bool HASOUT>
__global__ void edge_scatter(const float* __restrict__ cart,
                             const int* __restrict__ nl,
                             const float* __restrict__ shifts,
                             const int* __restrict__ species,
                             const float* __restrict__ g_rs,
                             const float* __restrict__ g_inta,
                             const float* __restrict__ g_par,
                             const float* __restrict__ outp,   // [A,24], only if HASOUT
                             float* __restrict__ orb,          // [A,13,8]
                             int E)
{
    __shared__ float s_rs[32], s_in[32], s_pa[32];
    if (threadIdx.x < 32) {
        s_rs[threadIdx.x] = g_rs[threadIdx.x];
        s_in[threadIdx.x] = g_inta[threadIdx.x];
        s_pa[threadIdx.x] = g_par[threadIdx.x];
    }
    __syncthreads();
    int e = blockIdx.x * blockDim.x + threadIdx.x;
    if (e >= E) return;

    int c = nl[e];
    int n = nl[E + e];
    float dx = cart[3*c+0] - cart[3*n+0] - shifts[3*e+0];
    float dy = cart[3*c+1] - cart[3*n+1] - shifts[3*e+1];
    float dz = cart[3*c+2] - cart[3*n+2] - shifts[3*e+2];
    float r  = sqrtf(dx*dx + dy*dy + dz*dz);

    float fcb = 0.5f * cosf(r * 0.6283185307179586f) + 0.5f;  // pi/CUTOFF = pi/5
    float fc  = fcb * fcb;

    int sb = species[n] * NW;
    float g[NW];
    #pragma unroll
    for (int w = 0; w < NW; ++w) {
        float dr = r - s_rs[sb + w];
        g[w] = __expf(-s_in[sb + w] * dr * dr) * s_pa[sb + w];
    }

    // per-ipsin gaussian (optionally modulated by output[neigh])
    float gw[3][NW];
    #pragma unroll
    for (int i = 0; i < 3; ++i) {
        #pragma unroll
        for (int w = 0; w < NW; ++w) {
            gw[i][w] = HASOUT ? g[w] * outp[(size_t)n * NATOM_FEAT + i * NW + w]
                              : g[w];
        }
    }

    float ang[PORI];
    ang[0] = 1.0f;
    ang[1] = dx;  ang[2] = dy;  ang[3] = dz;
    ang[4] = dx*dx; ang[5] = dx*dy; ang[6] = dx*dz;
    ang[7] = dy*dx; ang[8] = dy*dy; ang[9] = dy*dz;
    ang[10]= dz*dx; ang[11]= dz*dy; ang[12]= dz*dz;

    float* dst = orb + (size_t)c * (PORI * NW);
    #pragma unroll
    for (int p = 0; p < PORI; ++p) {
        const int ip = (p == 0) ? 0 : ((p < 4) ? 1 : 2);
        float cf = ang[p] * fc;
        #pragma unroll
        for (int w = 0; w < NW; ++w) {
            unsafeAtomicAdd(dst + p * NW + w, cf * gw[ip][w]);
        }
    }
}

// -------- density: squared group-sum over p within each ipsin group --------
__global__ void density_k(const float* __restrict__ orb, float* __restrict__ dens, int A)
{
    int idx = blockIdx.x * blockDim.x + threadIdx.x;  // a*24 + i*8 + w
    if (idx >= A * NATOM_FEAT) return;
    int a  = idx / NATOM_FEAT;
    int iw = idx - a * NATOM_FEAT;
    int i  = iw >> 3;
    int w  = iw & 7;
    const float* o = orb + (size_t)a * (PORI * NW) + w;
    float s = 0.0f;
    if (i == 0) {
        float v = o[0]; s = v * v;
    } else if (i == 1) {
        #pragma unroll
        for (int p = 1; p < 4; ++p) { float v = o[p * NW]; s += v * v; }
    } else {
        #pragma unroll
        for (int p = 4; p < 13; ++p) { float v = o[p * NW]; s += v * v; }
    }
    dens[idx] = s;
}

// -------- MLP: out = tanh(dens @ w1 + b1) @ w2 + b2, one thread per atom --------
__global__ void mlp_k(const float* __restrict__ dens,
                      const float* __restrict__ w1, const float* __restrict__ b1,
                      const float* __restrict__ w2, const float* __restrict__ b2,
                      float* __restrict__ outp, int A)
{
    int a = blockIdx.x * blockDim.x + threadIdx.x;
    if (a >= A) return;
    float d[NATOM_FEAT];
    #pragma unroll
    for (int j = 0; j < NATOM_FEAT; ++j) d[j] = dens[(size_t)a * NATOM_FEAT + j];
    float o[NATOM_FEAT];
    #pragma unroll
    for (int j = 0; j < NATOM_FEAT; ++j) o[j] = b2[j];

    for (int h = 0; h < HID; ++h) {
        float acc = b1[h];
        #pragma unroll
        for (int j = 0; j < NATOM_FEAT; ++j) acc += d[j] * w1[j * HID + h];
        float t = tanhf(acc);
        #pragma unroll
        for (int j = 0; j < NATOM_FEAT; ++j) o[j] += t * w2[h * NATOM_FEAT + j];
    }
    #pragma unroll
    for (int j = 0; j < NATOM_FEAT; ++j) outp[(size_t)a * NATOM_FEAT + j] = o[j];
}

extern "C" void kernel_launch(void* const* d_in, const int* in_sizes, int n_in,
                              void* d_out, int out_size, void* d_ws, size_t ws_size,
                              hipStream_t stream)
{
    const float* cart    = (const float*)d_in[0];
    const int*   nl      = (const int*)d_in[1];
    const float* shifts  = (const float*)d_in[2];
    const int*   species = (const int*)d_in[3];
    const float* rs      = (const float*)d_in[4];
    const float* inta    = (const float*)d_in[5];
    const float* params  = (const float*)d_in[6];
    const float* w1_0 = (const float*)d_in[7];
    const float* b1_0 = (const float*)d_in[8];
    const float* w2_0 = (const float*)d_in[9];
    const float* b2_0 = (const float*)d_in[10];
    const float* w1_1 = (const float*)d_in[11];
    const float* b1_1 = (const float*)d_in[12];
    const float* w2_1 = (const float*)d_in[13];
    const float* b2_1 = (const float*)d_in[14];

    const int A = in_sizes[0] / 3;
    const int E = in_sizes[1] / 2;

    float* orb  = (float*)d_ws;                          // [A,13,8]
    float* dens = orb + (size_t)A * (PORI * NW);         // [A,24]
    float* outp = dens + (size_t)A * NATOM_FEAT;         // [A,24]
    float* dout = (float*)d_out;                         // final density [A,24]

    const int BLK = 256;
    const int gridE = (E + BLK - 1) / BLK;
    const int gridD = (A * NATOM_FEAT + BLK - 1) / BLK;
    const int gridM = (A + BLK - 1) / BLK;
    const size_t orbBytes = (size_t)A * (PORI * NW) * sizeof(float);

    // ---- pass 0 ----
    hipMemsetAsync(orb, 0, orbBytes, stream);
    edge_scatter<false><<<gridE, BLK, 0, stream>>>(cart, nl, shifts, species, rs, inta, params,
                                                   nullptr, orb, E);
    density_k<<<gridD, BLK, 0, stream>>>(orb, dens, A);

    // ---- pass 1 ----
    mlp_k<<<gridM, BLK, 0, stream>>>(dens, w1_0, b1_0, w2_0, b2_0, outp, A);
    hipMemsetAsync(orb, 0, orbBytes, stream);
    edge_scatter<true><<<gridE, BLK, 0, stream>>>(cart, nl, shifts, species, rs, inta, params,
                                                  outp, orb, E);
    density_k<<<gridD, BLK, 0, stream>>>(orb, dens, A);

    // ---- pass 2 (final -> d_out) ----
    mlp_k<<<gridM, BLK, 0, stream>>>(dens, w1_1, b1_1, w2_1, b2_1, outp, A);
    hipMemsetAsync(orb, 0, orbBytes, stream);
    edge_scatter<true><<<gridE, BLK, 0, stream>>>(cart, nl, shifts, species, rs, inta, params,
                                                  outp, orb, E);
    density_k<<<gridD, BLK, 0, stream>>>(orb, dout, A);
}

// Round 3
// 440.838 us; speedup vs baseline: 18.6893x; 18.6893x over previous
//
#include <hip/hip_runtime.h>
#include <math.h>

#define NATOM_FEAT 24   // IPSIN * NWAVE = 3*8
#define PORI 13
#define NW 8
#define HID 128
#define CH 64           // edges staged per LDS chunk
#define SCAN_T 1024

// ---------------- CSR build ----------------
__global__ void csr_count(const int* __restrict__ nl, int* __restrict__ counts, int E)
{
    int e = blockIdx.x * blockDim.x + threadIdx.x;
    if (e < E) atomicAdd(&counts[nl[e]], 1);
}

__global__ void csr_scan(const int* __restrict__ counts, int* __restrict__ rowptr, int A)
{
    __shared__ int lds[SCAN_T];
    int tid = threadIdx.x;
    int chunk = (A + SCAN_T - 1) / SCAN_T;
    int base = tid * chunk;
    int own = 0;
    for (int i = 0; i < chunk; ++i) {
        int idx = base + i;
        if (idx < A) own += counts[idx];
    }
    lds[tid] = own;
    __syncthreads();
    // inclusive Hillis-Steele scan
    for (int off = 1; off < SCAN_T; off <<= 1) {
        int v = (tid >= off) ? lds[tid - off] : 0;
        __syncthreads();
        lds[tid] += v;
        __syncthreads();
    }
    int running = lds[tid] - own;   // exclusive prefix for this thread's chunk
    for (int i = 0; i < chunk; ++i) {
        int idx = base + i;
        if (idx < A) { rowptr[idx] = running; running += counts[idx]; }
    }
    if (tid == SCAN_T - 1) rowptr[A] = lds[SCAN_T - 1];
}

__global__ void csr_fill(const int* __restrict__ nl, const int* __restrict__ rowptr,
                         int* __restrict__ fill, int* __restrict__ snb,
                         int* __restrict__ seid, int E)
{
    int e = blockIdx.x * blockDim.x + threadIdx.x;
    if (e >= E) return;
    int c = nl[e];
    int ofs = atomicAdd(&fill[c], 1);
    int slot = rowptr[c] + ofs;
    snb[slot]  = nl[E + e];
    seid[slot] = e;
}

// ---------------- fused per-atom pass: gather edges -> orbital -> density ----------------
template<bool HASOUT>
__global__ __launch_bounds__(128)
void atom_pass(const float* __restrict__ cart,
               const float* __restrict__ shifts,
               const int* __restrict__ species,
               const float* __restrict__ g_rs,
               const float* __restrict__ g_inta,
               const float* __restrict__ g_par,
               const int* __restrict__ rowptr,
               const int* __restrict__ snb,
               const int* __restrict__ seid,
               const float* __restrict__ outp,   // [A,24] if HASOUT
               float* __restrict__ dens,         // [A,24]
               int A)
{
    __shared__ float s_rs[32], s_in[32], s_pa[32];
    __shared__ float ls_dx[CH], ls_dy[CH], ls_dz[CH], ls_fc[CH], ls_r[CH];
    __shared__ int   ls_n[CH], ls_sp[CH];
    __shared__ float orb_s[PORI][NW];

    int tid = threadIdx.x;
    if (tid < 32) {
        s_rs[tid] = g_rs[tid];
        s_in[tid] = g_inta[tid];
        s_pa[tid] = g_par[tid];
    }

    int a = blockIdx.x;
    float cax = cart[3*a+0], cay = cart[3*a+1], caz = cart[3*a+2];
    int s0 = rowptr[a], s1 = rowptr[a+1];

    int f = tid;                     // f = p*8 + w, valid for f < 104
    int p = f >> 3, w = f & 7;
    int ip = (p == 0) ? 0 : ((p < 4) ? 1 : 2);
    int a1 = (p >= 4) ? (p - 4) / 3 : 0;   // outer-product row
    int a2 = (p >= 4) ? (p - 4) % 3 : 0;   // outer-product col
    float acc = 0.0f;
    __syncthreads();

    for (int s = s0; s < s1; s += CH) {
        int m = min(CH, s1 - s);
        if (tid < m) {
            int n = snb[s + tid];
            int e = seid[s + tid];
            float dx = cax - cart[3*n+0] - shifts[3*e+0];
            float dy = cay - cart[3*n+1] - shifts[3*e+1];
            float dz = caz - cart[3*n+2] - shifts[3*e+2];
            float r  = sqrtf(dx*dx + dy*dy + dz*dz);
            float fcb = 0.5f * cosf(r * 0.6283185307179586f) + 0.5f;
            ls_dx[tid] = dx; ls_dy[tid] = dy; ls_dz[tid] = dz;
            ls_r[tid]  = r;  ls_fc[tid] = fcb * fcb;
            ls_n[tid]  = n;  ls_sp[tid] = species[n];
        }
        __syncthreads();
        if (f < PORI * NW) {
            for (int j = 0; j < m; ++j) {
                float d3[3] = { ls_dx[j], ls_dy[j], ls_dz[j] };
                float r  = ls_r[j];
                float fc = ls_fc[j];
                int sb = ls_sp[j] * NW + w;
                float dr = r - s_rs[sb];
                float g  = __expf(-s_in[sb] * dr * dr) * s_pa[sb];
                float ang = (p == 0) ? 1.0f : ((p < 4) ? d3[p-1] : d3[a1] * d3[a2]);
                float v = ang * fc * g;
                if (HASOUT) v *= outp[(size_t)ls_n[j] * NATOM_FEAT + ip * NW + w];
                acc += v;
            }
        }
        __syncthreads();
    }

    if (f < PORI * NW) orb_s[p][w] = acc * acc;
    __syncthreads();
    if (tid < NATOM_FEAT) {
        int i = tid >> 3, ww = tid & 7;
        float sum;
        if (i == 0) {
            sum = orb_s[0][ww];
        } else if (i == 1) {
            sum = orb_s[1][ww] + orb_s[2][ww] + orb_s[3][ww];
        } else {
            sum = 0.0f;
            #pragma unroll
            for (int q = 4; q < PORI; ++q) sum += orb_s[q][ww];
        }
        dens[(size_t)a * NATOM_FEAT + tid] = sum;
    }
}

// ---------------- MLP: out = tanh(dens @ w1 + b1) @ w2 + b2 ----------------
__global__ void mlp_k(const float* __restrict__ dens,
                      const float* __restrict__ w1, const float* __restrict__ b1,
                      const float* __restrict__ w2, const float* __restrict__ b2,
                      float* __restrict__ outp, int A)
{
    int a = blockIdx.x * blockDim.x + threadIdx.x;
    if (a >= A) return;
    float d[NATOM_FEAT];
    #pragma unroll
    for (int j = 0; j < NATOM_FEAT; ++j) d[j] = dens[(size_t)a * NATOM_FEAT + j];
    float o[NATOM_FEAT];
    #pragma unroll
    for (int j = 0; j < NATOM_FEAT; ++j) o[j] = b2[j];

    for (int h = 0; h < HID; ++h) {
        float acc = b1[h];
        #pragma unroll
        for (int j = 0; j < NATOM_FEAT; ++j) acc += d[j] * w1[j * HID + h];
        float t = tanhf(acc);
        #pragma unroll
        for (int j = 0; j < NATOM_FEAT; ++j) o[j] += t * w2[h * NATOM_FEAT + j];
    }
    #pragma unroll
    for (int j = 0; j < NATOM_FEAT; ++j) outp[(size_t)a * NATOM_FEAT + j] = o[j];
}

extern "C" void kernel_launch(void* const* d_in, const int* in_sizes, int n_in,
                              void* d_out, int out_size, void* d_ws, size_t ws_size,
                              hipStream_t stream)
{
    const float* cart    = (const float*)d_in[0];
    const int*   nl      = (const int*)d_in[1];
    const float* shifts  = (const float*)d_in[2];
    const int*   species = (const int*)d_in[3];
    const float* rs      = (const float*)d_in[4];
    const float* inta    = (const float*)d_in[5];
    const float* params  = (const float*)d_in[6];
    const float* w1_0 = (const float*)d_in[7];
    const float* b1_0 = (const float*)d_in[8];
    const float* w2_0 = (const float*)d_in[9];
    const float* b2_0 = (const float*)d_in[10];
    const float* w1_1 = (const float*)d_in[11];
    const float* b1_1 = (const float*)d_in[12];
    const float* w2_1 = (const float*)d_in[13];
    const float* b2_1 = (const float*)d_in[14];

    const int A = in_sizes[0] / 3;
    const int E = in_sizes[1] / 2;

    // workspace layout (ints and floats are both 4B)
    char* ws = (char*)d_ws;
    int*   counts = (int*)ws;                 ws += (size_t)A * 4;
    int*   fill   = (int*)ws;                 ws += (size_t)A * 4;
    int*   rowptr = (int*)ws;                 ws += (size_t)(A + 1) * 4;
    int*   snb    = (int*)ws;                 ws += (size_t)E * 4;
    int*   seid   = (int*)ws;                 ws += (size_t)E * 4;
    float* dens   = (float*)ws;               ws += (size_t)A * NATOM_FEAT * 4;
    float* outp   = (float*)ws;               ws += (size_t)A * NATOM_FEAT * 4;
    float* dout   = (float*)d_out;

    const int BLK = 256;
    const int gridE = (E + BLK - 1) / BLK;
    const int gridM = (A + BLK - 1) / BLK;

    // ---- CSR build (once per launch) ----
    hipMemsetAsync(counts, 0, (size_t)A * 4, stream);
    hipMemsetAsync(fill,   0, (size_t)A * 4, stream);
    csr_count<<<gridE, BLK, 0, stream>>>(nl, counts, E);
    csr_scan<<<1, SCAN_T, 0, stream>>>(counts, rowptr, A);
    csr_fill<<<gridE, BLK, 0, stream>>>(nl, rowptr, fill, snb, seid, E);

    // ---- pass 0 ----
    atom_pass<false><<<A, 128, 0, stream>>>(cart, shifts, species, rs, inta, params,
                                            rowptr, snb, seid, nullptr, dens, A);
    // ---- pass 1 ----
    mlp_k<<<gridM, BLK, 0, stream>>>(dens, w1_0, b1_0, w2_0, b2_0, outp, A);
    atom_pass<true><<<A, 128, 0, stream>>>(cart, shifts, species, rs, inta, params,
                                           rowptr, snb, seid, outp, dens, A);
    // ---- pass 2 (final -> d_out) ----
    mlp_k<<<gridM, BLK, 0, stream>>>(dens, w1_1, b1_1, w2_1, b2_1, outp, A);
    atom_pass<true><<<A, 128, 0, stream>>>(cart, shifts, species, rs, inta, params,
                                           rowptr, snb, seid, outp, dout, A);
}

// Round 4
// 373.423 us; speedup vs baseline: 22.0633x; 1.1805x over previous
//
#include <hip/hip_runtime.h>
#include <math.h>

#define NATOM_FEAT 24   // IPSIN * NWAVE = 3*8
#define PORI 13
#define NW 8
#define HID 128
#define CH 64           // edges staged per LDS chunk
#define SCAN_T 1024
#define TA 32           // atoms per MLP block

// ---------------- CSR build ----------------
__global__ void csr_count(const int* __restrict__ nl, int* __restrict__ counts, int E)
{
    int e = blockIdx.x * blockDim.x + threadIdx.x;
    if (e < E) atomicAdd(&counts[nl[e]], 1);
}

__global__ void csr_scan(const int* __restrict__ counts, int* __restrict__ rowptr, int A)
{
    __shared__ int lds[SCAN_T];
    int tid = threadIdx.x;
    int chunk = (A + SCAN_T - 1) / SCAN_T;
    int base = tid * chunk;
    int own = 0;
    for (int i = 0; i < chunk; ++i) {
        int idx = base + i;
        if (idx < A) own += counts[idx];
    }
    lds[tid] = own;
    __syncthreads();
    for (int off = 1; off < SCAN_T; off <<= 1) {
        int v = (tid >= off) ? lds[tid - off] : 0;
        __syncthreads();
        lds[tid] += v;
        __syncthreads();
    }
    int running = lds[tid] - own;
    for (int i = 0; i < chunk; ++i) {
        int idx = base + i;
        if (idx < A) { rowptr[idx] = running; running += counts[idx]; }
    }
    if (tid == SCAN_T - 1) rowptr[A] = lds[SCAN_T - 1];
}

// fill CSR slots AND precompute per-edge geometry + fc-folded gaussians (once, reused 3x)
__global__ void csr_fill_geom(const int* __restrict__ nl, const int* __restrict__ rowptr,
                              int* __restrict__ fill,
                              const float* __restrict__ cart,
                              const float* __restrict__ shifts,
                              const int* __restrict__ species,
                              const float* __restrict__ g_rs,
                              const float* __restrict__ g_inta,
                              const float* __restrict__ g_par,
                              float4* __restrict__ geom,     // [E] {dx,dy,dz, n-as-float-bits}
                              float4* __restrict__ gauss,    // [2E] g[0..7] * fc
                              int E)
{
    int e = blockIdx.x * blockDim.x + threadIdx.x;
    if (e >= E) return;
    int c = nl[e];
    int n = nl[E + e];
    float dx = cart[3*c+0] - cart[3*n+0] - shifts[3*e+0];
    float dy = cart[3*c+1] - cart[3*n+1] - shifts[3*e+1];
    float dz = cart[3*c+2] - cart[3*n+2] - shifts[3*e+2];
    float r  = sqrtf(dx*dx + dy*dy + dz*dz);
    float fcb = 0.5f * cosf(r * 0.6283185307179586f) + 0.5f;   // pi/5
    float fc  = fcb * fcb;
    int sb = species[n] * NW;
    float g[NW];
    #pragma unroll
    for (int w = 0; w < NW; ++w) {
        float dr = r - g_rs[sb + w];
        g[w] = __expf(-g_inta[sb + w] * dr * dr) * g_par[sb + w] * fc;
    }
    int ofs  = atomicAdd(&fill[c], 1);
    int slot = rowptr[c] + ofs;
    geom[slot] = make_float4(dx, dy, dz, __int_as_float(n));
    gauss[2*slot+0] = make_float4(g[0], g[1], g[2], g[3]);
    gauss[2*slot+1] = make_float4(g[4], g[5], g[6], g[7]);
}

// ---------------- fused per-atom pass: gather precomputed edges -> orbital -> density ----------------
template<bool HASOUT>
__global__ __launch_bounds__(128)
void atom_pass(const float4* __restrict__ geom,
               const float4* __restrict__ gauss,
               const int* __restrict__ rowptr,
               const float* __restrict__ outp,   // [A,24] if HASOUT
               float* __restrict__ dens,         // [A,24]
               int A)
{
    __shared__ float4 ls_gm[CH];
    __shared__ float4 ls_g[CH][2];
    __shared__ float  orb_s[PORI][NW];

    int tid = threadIdx.x;
    int a = blockIdx.x;
    int s0 = rowptr[a], s1 = rowptr[a+1];

    int f = tid;                     // f = p*8 + w, valid for f < 104
    int p = f >> 3, w = f & 7;
    int ip = (p == 0) ? 0 : ((p < 4) ? 1 : 2);
    // angular factor indices: -1 means "multiply by 1"
    int bi1 = (p == 0) ? -1 : ((p < 4) ? (p - 1) : (p - 4) / 3);
    int bi2 = (p < 4) ? -1 : (p - 4) % 3;
    float acc = 0.0f;

    for (int s = s0; s < s1; s += CH) {
        int m = min(CH, s1 - s);
        if (tid < m) {
            ls_gm[tid]   = geom[s + tid];
            ls_g[tid][0] = gauss[2*(s + tid) + 0];
            ls_g[tid][1] = gauss[2*(s + tid) + 1];
        }
        __syncthreads();
        if (f < PORI * NW) {
            for (int j = 0; j < m; ++j) {
                float4 G = ls_gm[j];
                float gg = ((const float*)ls_g[j])[w];
                float v1 = (bi1 == 0) ? G.x : ((bi1 == 1) ? G.y : ((bi1 == 2) ? G.z : 1.0f));
                float v2 = (bi2 == 0) ? G.x : ((bi2 == 1) ? G.y : ((bi2 == 2) ? G.z : 1.0f));
                float v = v1 * v2 * gg;
                if (HASOUT) {
                    int n = __float_as_int(G.w);
                    v *= outp[(size_t)n * NATOM_FEAT + ip * NW + w];
                }
                acc += v;
            }
        }
        __syncthreads();
    }

    if (f < PORI * NW) orb_s[p][w] = acc * acc;
    __syncthreads();
    if (tid < NATOM_FEAT) {
        int i = tid >> 3, ww = tid & 7;
        float sum;
        if (i == 0) {
            sum = orb_s[0][ww];
        } else if (i == 1) {
            sum = orb_s[1][ww] + orb_s[2][ww] + orb_s[3][ww];
        } else {
            sum = 0.0f;
            #pragma unroll
            for (int q = 4; q < PORI; ++q) sum += orb_s[q][ww];
        }
        dens[(size_t)a * NATOM_FEAT + tid] = sum;
    }
}

// ---------------- MLP: outp = tanh(dens @ w1 + b1) @ w2 + b2 ; tiled, 32 atoms/block ----------------
__global__ __launch_bounds__(256)
void mlp_k(const float* __restrict__ dens,
           const float* __restrict__ w1, const float* __restrict__ b1,
           const float* __restrict__ w2, const float* __restrict__ b2,
           float* __restrict__ outp, int A)
{
    __shared__ float d_s[TA][NATOM_FEAT];    // 32x24
    __shared__ float t_s[TA][HID + 1];       // 32x129 (pad kills phase-C bank conflict)
    int tid = threadIdx.x;
    int a0 = blockIdx.x * TA;

    // load dens tile (coalesced)
    for (int i = tid; i < TA * NATOM_FEAT; i += 256) {
        int gidx = a0 * NATOM_FEAT + i;
        ((float*)d_s)[i] = (gidx < A * NATOM_FEAT) ? dens[gidx] : 0.0f;
    }
    __syncthreads();

    // phase B: hidden activations, (a,h) tasks = 32*128 = 4096
    #pragma unroll
    for (int k = 0; k < TA * HID / 256; ++k) {
        int task = tid + k * 256;
        int a = task >> 7;       // /HID
        int h = task & (HID - 1);
        float acc = b1[h];
        #pragma unroll
        for (int j = 0; j < NATOM_FEAT; ++j) acc += d_s[a][j] * w1[j * HID + h];
        float e = __expf(2.0f * acc);
        t_s[a][h] = 1.0f - 2.0f / (e + 1.0f);   // tanh, saturates correctly at +-inf
    }
    __syncthreads();

    // phase C: outputs, (a,j) tasks = 32*24 = 768
    #pragma unroll
    for (int k = 0; k < 3; ++k) {
        int task = tid + k * 256;
        int a = task / NATOM_FEAT;
        int j = task - a * NATOM_FEAT;
        float o = b2[j];
        #pragma unroll 8
        for (int h = 0; h < HID; ++h) o += t_s[a][h] * w2[h * NATOM_FEAT + j];
        int gidx = a0 * NATOM_FEAT + task;
        if (gidx < A * NATOM_FEAT) outp[gidx] = o;   // coalesced (task is linear)
    }
}

extern "C" void kernel_launch(void* const* d_in, const int* in_sizes, int n_in,
                              void* d_out, int out_size, void* d_ws, size_t ws_size,
                              hipStream_t stream)
{
    const float* cart    = (const float*)d_in[0];
    const int*   nl      = (const int*)d_in[1];
    const float* shifts  = (const float*)d_in[2];
    const int*   species = (const int*)d_in[3];
    const float* rs      = (const float*)d_in[4];
    const float* inta    = (const float*)d_in[5];
    const float* params  = (const float*)d_in[6];
    const float* w1_0 = (const float*)d_in[7];
    const float* b1_0 = (const float*)d_in[8];
    const float* w2_0 = (const float*)d_in[9];
    const float* b2_0 = (const float*)d_in[10];
    const float* w1_1 = (const float*)d_in[11];
    const float* b1_1 = (const float*)d_in[12];
    const float* w2_1 = (const float*)d_in[13];
    const float* b2_1 = (const float*)d_in[14];

    const int A = in_sizes[0] / 3;
    const int E = in_sizes[1] / 2;

    // workspace layout — 16B-aligned arrays first
    char* ws = (char*)d_ws;
    float4* geom  = (float4*)ws;              ws += (size_t)E * 16;
    float4* gauss = (float4*)ws;              ws += (size_t)E * 32;
    int*   counts = (int*)ws;                 ws += (size_t)A * 4;
    int*   fill   = (int*)ws;                 ws += (size_t)A * 4;
    int*   rowptr = (int*)ws;                 ws += (size_t)(A + 1) * 4;
    float* dens   = (float*)ws;               ws += (size_t)A * NATOM_FEAT * 4;
    float* outp   = (float*)ws;               ws += (size_t)A * NATOM_FEAT * 4;
    float* dout   = (float*)d_out;

    const int BLK = 256;
    const int gridE = (E + BLK - 1) / BLK;
    const int gridM = (A + TA - 1) / TA;

    // ---- CSR build + per-edge precompute (once) ----
    hipMemsetAsync(counts, 0, (size_t)A * 4, stream);
    hipMemsetAsync(fill,   0, (size_t)A * 4, stream);
    csr_count<<<gridE, BLK, 0, stream>>>(nl, counts, E);
    csr_scan<<<1, SCAN_T, 0, stream>>>(counts, rowptr, A);
    csr_fill_geom<<<gridE, BLK, 0, stream>>>(nl, rowptr, fill, cart, shifts, species,
                                             rs, inta, params, geom, gauss, E);

    // ---- pass 0 ----
    atom_pass<false><<<A, 128, 0, stream>>>(geom, gauss, rowptr, nullptr, dens, A);
    // ---- pass 1 ----
    mlp_k<<<gridM, 256, 0, stream>>>(dens, w1_0, b1_0, w2_0, b2_0, outp, A);
    atom_pass<true><<<A, 128, 0, stream>>>(geom, gauss, rowptr, outp, dens, A);
    // ---- pass 2 (final -> d_out) ----
    mlp_k<<<gridM, 256, 0, stream>>>(dens, w1_1, b1_1, w2_1, b2_1, outp, A);
    atom_pass<true><<<A, 128, 0, stream>>>(geom, gauss, rowptr, outp, dout, A);
}